// Round 7
// baseline (131.952 us; speedup 1.0000x reference)
//
#include <hip/hip_runtime.h>
#include <hip/hip_bf16.h>

#define B_ 128
#define S_ 513
#define H_ 256
#define SH_ (S_ * H_)

typedef __attribute__((ext_vector_type(8))) short short8;
typedef __attribute__((ext_vector_type(4))) float f32x4;

// Pack 8 fp32 -> 8 bf16 (RNE) via the HW packed converter.
static __device__ inline short8 pack8(float4 a, float4 b) {
    union { short8 s; __hip_bfloat162 h[4]; } u;
    u.h[0] = __float22bfloat162_rn(make_float2(a.x, a.y));
    u.h[1] = __float22bfloat162_rn(make_float2(a.z, a.w));
    u.h[2] = __float22bfloat162_rn(make_float2(b.x, b.y));
    u.h[3] = __float22bfloat162_rn(make_float2(b.z, b.w));
    return u.s;
}
static __device__ inline short8 pack8v(f32x4 a, f32x4 b) {
    union { short8 s; __hip_bfloat162 h[4]; } u;
    u.h[0] = __float22bfloat162_rn(make_float2(a[0], a[1]));
    u.h[1] = __float22bfloat162_rn(make_float2(a[2], a[3]));
    u.h[2] = __float22bfloat162_rn(make_float2(b[0], b[1]));
    u.h[3] = __float22bfloat162_rn(make_float2(b[2], b[3]));
    return u.s;
}

// Prep: W fp32 -> bf16 in fragment-major layout (m, kc, d, 8) so the main
// kernel's W fragment loads are coalesced (16 lanes -> 256 B run).
// Also bias sum (256 floats).
__global__ void prep_kernel(const float* __restrict__ W,
                            const float* __restrict__ bias,
                            unsigned short* __restrict__ Wbf,
                            float* __restrict__ bsum) {
    int t = blockIdx.x * 256 + threadIdx.x;
    if (t < 5 * 32 * 256) {                 // one thread per (m, d, kc)
        int m  = t >> 13;                   // t / 8192
        int r  = t & 8191;
        int d  = r >> 5;
        int kc = r & 31;                    // 8-elem k-chunk
        const float* src = W + (((size_t)m * 256 + d) * 256 + kc * 8);
        float4 v0 = *(const float4*)src;
        float4 v1 = *(const float4*)(src + 4);
        *(short8*)(Wbf + ((size_t)(m * 32 + kc) * 256 + d) * 8) = pack8(v0, v1);
    }
    if (t < H_) {
        float s = 0.f;
#pragma unroll
        for (int i = 0; i < 5; ++i) s += bias[i * H_ + t];
        bsum[t] = s;
    }
}

// R0-R5 diagnostic: duration tracks HBM bytes at a flat ~2.4-2.5 TB/s across
// every structure; the harness's own fill kernel hits 6.6 TB/s at 8.6%
// occupancy -> BW is gated by ISSUE DEPTH, not occupancy/contiguity. Every
// prior version was VGPR-throttled in staging (VGPR_Count=64 -> <=8 loads in
// flight). This version stages x fp32 DIRECTLY into LDS via
// global_load_lds_dwordx4: no VGPR round-trip, each wave issues its full
// 8 KB in 8 fire-and-forget instructions -> 32 KB outstanding per block,
// ~128 KB/CU at 4 blocks/CU. bf16 conversion moves into the K-loop (cvt_pk
// under MFMA co-issue; VALUBusy was 5%).
//
// gload_lds needs a LINEAR LDS dest (wave-uniform base + lane*16), so the
// bank-conflict swizzle moves to the GLOBAL source (m173 pattern): LDS 16B
// chunk c of row r receives global chunk c ^ (r&7); fragment reads apply the
// same XOR -> 2 lanes/bank (free). No ds_writes remain.
//
// Decomposition: b-major (R5). bid<2048: b=bid>>4, par=(bid&1): s-rows
// sbase=(par?3:4)+tile*64 stride 2, M=32, W3/W4 by parity. 12 edge blocks
// cover s in {0,1,2} (W0/W1/W2) over b-rows.
template <int MODE>
__global__ __launch_bounds__(256, 4)
void sel_gemm_kernel(const float* __restrict__ x,
                     const void* __restrict__ Wp,
                     const void* __restrict__ bp,
                     float* __restrict__ out) {
    const int bid = blockIdx.x;
    int m_idx, rmax, rowstride;
    size_t rowbase;
    if (bid < 2048) {
        const int b    = bid >> 4;
        const int sub  = bid & 15;
        const int par  = sub & 1;
        const int tile = sub >> 1;          // 0..7
        const int sbase = (par ? 3 : 4) + tile * 64;
        m_idx     = par ? 3 : 4;
        rowbase   = (size_t)b * S_ + sbase;
        rowstride = 2;
        rmax      = (512 - sbase) >> 1;
        if (rmax > 31) rmax = 31;
    } else {
        const int e  = bid - 2048;          // 0..11
        const int s  = e >> 2;              // 0..2
        const int bq = e & 3;
        m_idx     = s;
        rowbase   = (size_t)(bq * 32) * S_ + s;
        rowstride = S_;
        rmax      = 31;
    }

    // 32 rows x 256 fp32 = 32 KB, staged by global_load_lds (linear dest).
    __shared__ float As[32 * 256];

    const int t    = threadIdx.x;
    const int lane = t & 63;
    const int w    = t >> 6;        // 0..3 : d-slice (w*64)
    const int lrow = lane & 15;
    const int quad = lane >> 4;

    // ---- Stage: one full row (1 KB) per wave-instruction, 8 per wave.
    // Row r is wave-uniform; per-lane GLOBAL chunk = lane ^ (r&7) so that
    // LDS chunk c holds global chunk c ^ (r&7). Fire-and-forget: no VGPRs.
#pragma unroll
    for (int it = 0; it < 8; ++it) {
        const int r  = it * 4 + w;
        const int rc = r <= rmax ? r : rmax;   // clamped data, slot r stays r
        const float* src = x + (rowbase + (size_t)rowstride * rc) * H_
                             + ((lane ^ (r & 7)) << 2);
        __builtin_amdgcn_global_load_lds(
            (const __attribute__((address_space(1))) unsigned int*)src,
            (__attribute__((address_space(3))) unsigned int*)&As[r * 256],
            16, 0, 0);
    }

    f32x4 acc[2][4];
#pragma unroll
    for (int i = 0; i < 2; ++i)
#pragma unroll
        for (int j = 0; j < 4; ++j) {
            f32x4 z = {0.f, 0.f, 0.f, 0.f};
            acc[i][j] = z;
        }

    __syncthreads();   // vmcnt(0) drain + barrier: LDS tile complete

    // ---- K-loop: 8 steps of 32. W frags from L2 (640 KB total, hot);
    // x frags read fp32 from LDS (XOR-deswizzled) and cvt_pk'd to bf16.
#pragma unroll
    for (int kk = 0; kk < 8; ++kk) {
        short8 wfr[4];
        if (MODE == 0) {
            // layout (m, kc, d, 8): lane reads d = w*64 + j*16 + lrow,
            // kc = kk*4 + quad -> 16 lanes = 256 B contiguous.
            const unsigned short* Wk =
                (const unsigned short*)Wp +
                ((size_t)(m_idx * 32 + kk * 4 + quad) * 256) * 8;
#pragma unroll
            for (int j = 0; j < 4; ++j)
                wfr[j] = *(const short8*)(Wk + (size_t)(w * 64 + j * 16 + lrow) * 8);
        } else {
            const float* Wb = (const float*)Wp + (size_t)m_idx * H_ * H_;
#pragma unroll
            for (int j = 0; j < 4; ++j) {
                const float* wrow = Wb + (size_t)(w * 64 + j * 16 + lrow) * H_
                                    + kk * 32 + quad * 8;
                float4 v0 = *(const float4*)wrow;
                float4 v1 = *(const float4*)(wrow + 4);
                wfr[j] = pack8(v0, v1);
            }
        }

        short8 xfr[2];
        const int g0 = kk * 8 + quad * 2;   // global 16B-chunk index, h=0
#pragma unroll
        for (int i = 0; i < 2; ++i) {
            const int r = i * 16 + lrow;
            f32x4 f0 = *(const f32x4*)&As[r * 256 + (((g0    ) ^ (r & 7)) << 2)];
            f32x4 f1 = *(const f32x4*)&As[r * 256 + (((g0 + 1) ^ (r & 7)) << 2)];
            xfr[i] = pack8v(f0, f1);
        }

#pragma unroll
        for (int j = 0; j < 4; ++j)
#pragma unroll
            for (int i = 0; i < 2; ++i)
                acc[i][j] = __builtin_amdgcn_mfma_f32_16x16x32_bf16(
                    wfr[j], xfr[i], acc[i][j], 0, 0, 0);
    }

    // ---- Epilogue. A=W, B=x -> col(lane&15)=tile row, row(quad*4+reg)=d.
    // Per (i,j): one float4 store along d, predicated on row validity.
#pragma unroll
    for (int j = 0; j < 4; ++j) {
        const int d0 = w * 64 + j * 16 + quad * 4;
        f32x4 bj;
        if (MODE == 0) {
            bj = *(const f32x4*)((const float*)bp + d0);
        } else {
            const float* bias = (const float*)bp;
#pragma unroll
            for (int r = 0; r < 4; ++r) {
                float sum = 0.f;
#pragma unroll
                for (int i = 0; i < 5; ++i) sum += bias[i * H_ + d0 + r];
                bj[r] = sum;
            }
        }
#pragma unroll
        for (int i = 0; i < 2; ++i) {
            const int r = i * 16 + lrow;
            if (r <= rmax) {
                f32x4 v = acc[i][j] + bj;
                *(f32x4*)(out + (rowbase + (size_t)rowstride * r) * H_ + d0) = v;
            }
        }
    }
}

extern "C" void kernel_launch(void* const* d_in, const int* in_sizes, int n_in,
                              void* d_out, int out_size, void* d_ws, size_t ws_size,
                              hipStream_t stream) {
    const float* x    = (const float*)d_in[0];
    const float* W    = (const float*)d_in[1];
    const float* bias = (const float*)d_in[2];
    float* out = (float*)d_out;

    const size_t w_elems  = (size_t)5 * H_ * H_;
    const size_t ws_need  = w_elems * sizeof(unsigned short) + H_ * sizeof(float);

    const int grid = 2048 + 12;
    if (ws_size >= ws_need) {
        unsigned short* Wbf = (unsigned short*)d_ws;
        float* bsum = (float*)((char*)d_ws + w_elems * sizeof(unsigned short));
        prep_kernel<<<dim3(160), dim3(256), 0, stream>>>(W, bias, Wbf, bsum);
        sel_gemm_kernel<0><<<dim3(grid), dim3(256), 0, stream>>>(
            x, (const void*)Wbf, (const void*)bsum, out);
    } else {
        sel_gemm_kernel<1><<<dim3(grid), dim3(256), 0, stream>>>(
            x, (const void*)W, (const void*)bias, out);
    }
}